// Round 9
// baseline (604.783 us; speedup 1.0000x reference)
//
#include <hip/hip_runtime.h>

#define NN 50000
#define NE 800000
#define DIM 512
#define MLPH 200

typedef __attribute__((ext_vector_type(8))) short short8;
typedef __attribute__((ext_vector_type(4))) float f32x4;

// async global->LDS, 16B per lane, wave-uniform LDS base (m97 pattern)
#define GL2LDS(g, l)                                                     \
    __builtin_amdgcn_global_load_lds(                                    \
        (const __attribute__((address_space(1))) unsigned int*)(g),      \
        (__attribute__((address_space(3))) unsigned int*)(l), 16, 0, 0)

__device__ inline unsigned short f2bf(float f) {
    unsigned int u = __float_as_uint(f);
    unsigned int r = (u + 0x7fffu + ((u >> 16) & 1u)) >> 16;
    return (unsigned short)r;
}
__device__ inline float bflo(unsigned u) { return __uint_as_float(u << 16); }
__device__ inline float bfhi(unsigned u) { return __uint_as_float(u & 0xffff0000u); }
__device__ inline unsigned pack2(float a, float b) {
    return (unsigned)f2bf(a) | ((unsigned)f2bf(b) << 16);
}

// ---------------- CSR build ----------------
__global__ void k_hist(const int* __restrict__ dst, int* __restrict__ counts) {
    int e = blockIdx.x * blockDim.x + threadIdx.x;
    if (e < NE) atomicAdd(&counts[dst[e]], 1);
}

__global__ void k_part(const int* __restrict__ counts, int* __restrict__ partial) {
    int t = threadIdx.x;
    int i = blockIdx.x * 256 + t;
    int x = (i < NN) ? counts[i] : 0;
#pragma unroll
    for (int off = 32; off; off >>= 1) x += __shfl_down(x, off);
    __shared__ int ws[4];
    if ((t & 63) == 0) ws[t >> 6] = x;
    __syncthreads();
    if (t == 0) partial[blockIdx.x] = ws[0] + ws[1] + ws[2] + ws[3];
}

__global__ void k_scanp(int* __restrict__ partial, int* __restrict__ rowstart, int nb) {
    __shared__ int ws[4];
    int t = threadIdx.x;
    int x = (t < nb) ? partial[t] : 0;
    int v = x;
#pragma unroll
    for (int off = 1; off < 64; off <<= 1) {
        int u = __shfl_up(v, off);
        if ((t & 63) >= off) v += u;
    }
    if ((t & 63) == 63) ws[t >> 6] = v;
    __syncthreads();
    int add = 0;
#pragma unroll
    for (int w = 0; w < 4; w++)
        if (w < (t >> 6)) add += ws[w];
    if (t < nb) partial[t] = v - x + add;  // exclusive
    if (t == 255) rowstart[NN] = v + add;  // total == NE
}

__global__ void k_scan2(const int* __restrict__ counts, const int* __restrict__ pexcl,
                        int* __restrict__ rowstart, int* __restrict__ cursor) {
    __shared__ int ws[4];
    int t = threadIdx.x;
    int i = blockIdx.x * 256 + t;
    int x = (i < NN) ? counts[i] : 0;
    int v = x;
#pragma unroll
    for (int off = 1; off < 64; off <<= 1) {
        int u = __shfl_up(v, off);
        if ((t & 63) >= off) v += u;
    }
    if ((t & 63) == 63) ws[t >> 6] = v;
    __syncthreads();
    int add = 0;
#pragma unroll
    for (int w = 0; w < 4; w++)
        if (w < (t >> 6)) add += ws[w];
    if (i < NN) {
        int r = pexcl[blockIdx.x] + v - x + add;
        rowstart[i] = r;
        cursor[i] = r;
    }
}

__global__ void k_fill(const int* __restrict__ src, const int* __restrict__ dst,
                       int* __restrict__ cursor, int* __restrict__ adj) {
    int e = blockIdx.x * blockDim.x + threadIdx.x;
    if (e < NE) {
        int p = atomicAdd(&cursor[dst[e]], 1);
        adj[p] = src[e];
    }
}

// ---------------- fp32 -> bf16 conversion (features, row-major) ----------------
__global__ void k_cvt(const float* __restrict__ in, ushort* __restrict__ out, int n4) {
    int i = blockIdx.x * blockDim.x + threadIdx.x;
    if (i >= n4) return;
    float4 v = *(const float4*)(in + (size_t)i * 4);
    ushort2 a{f2bf(v.x), f2bf(v.y)}, b{f2bf(v.z), f2bf(v.w)};
    *(ushort2*)(out + (size_t)i * 4) = a;
    *(ushort2*)(out + (size_t)i * 4 + 2) = b;
}

// ---------------- all three weight transposes in one kernel ----------------
__global__ void k_wt3(const float* __restrict__ W1, const float* __restrict__ W2,
                      const float* __restrict__ Wh, ushort* __restrict__ W1t,
                      ushort* __restrict__ W2t, ushort* __restrict__ Wht) {
    int i = blockIdx.x * 256 + threadIdx.x;
    const int S1 = 512 * 512, S2 = 2 * 512 * 512, S3 = 2 * 512 * 512 + MLPH * 512;
    if (i < S1) {
        int n = i >> 9, k = i & 511;
        W1t[i] = f2bf(W1[(size_t)k * 512 + n]);
    } else if (i < S2) {
        int j = i - S1, n = j >> 9, k = j & 511;
        W2t[j] = f2bf(W2[(size_t)k * 512 + n]);
    } else if (i < S3) {
        int j = i - S2, n = j >> 9, k = j & 511;
        Wht[j] = f2bf(Wh[(size_t)k * MLPH + n]);
    }
}

// ---------------- aggregation (row-major bf16, fp32 accum): (sum_nbr + 2*self)/(deg+2) ----------------
__device__ inline void addrow(float* acc, uint4 v) {
    acc[0] += bflo(v.x); acc[1] += bfhi(v.x);
    acc[2] += bflo(v.y); acc[3] += bfhi(v.y);
    acc[4] += bflo(v.z); acc[5] += bfhi(v.z);
    acc[6] += bflo(v.w); acc[7] += bfhi(v.w);
}

__global__ __launch_bounds__(256) void k_agg_bf(const ushort* __restrict__ h,
                                                const int* __restrict__ rowstart,
                                                const int* __restrict__ adj,
                                                ushort* __restrict__ out) {
    int node = blockIdx.x * 4 + (threadIdx.x >> 6);
    int lane = threadIdx.x & 63;
    if (node >= NN) return;
    int s = rowstart[node], e = rowstart[node + 1];
    const size_t coff = (size_t)lane * 8;
    float acc[8];
    {
        uint4 v = *(const uint4*)(h + (size_t)node * DIM + coff);
        acc[0] = 2.f * bflo(v.x); acc[1] = 2.f * bfhi(v.x);
        acc[2] = 2.f * bflo(v.y); acc[3] = 2.f * bfhi(v.y);
        acc[4] = 2.f * bflo(v.z); acc[5] = 2.f * bfhi(v.z);
        acc[6] = 2.f * bflo(v.w); acc[7] = 2.f * bfhi(v.w);
    }
    int i = s;
    int e4 = s + ((e - s) & ~3);
    for (; i < e4; i += 4) {
        int n0 = adj[i], n1 = adj[i + 1], n2 = adj[i + 2], n3 = adj[i + 3];
        uint4 v0 = *(const uint4*)(h + (size_t)n0 * DIM + coff);
        uint4 v1 = *(const uint4*)(h + (size_t)n1 * DIM + coff);
        uint4 v2 = *(const uint4*)(h + (size_t)n2 * DIM + coff);
        uint4 v3 = *(const uint4*)(h + (size_t)n3 * DIM + coff);
        addrow(acc, v0);
        addrow(acc, v1);
        addrow(acc, v2);
        addrow(acc, v3);
    }
    for (; i < e; i++) {
        int nbr = adj[i];
        uint4 v = *(const uint4*)(h + (size_t)nbr * DIM + coff);
        addrow(acc, v);
    }
    float inv = 1.0f / (float)(e - s + 2);
    uint4 o;
    o.x = pack2(acc[0] * inv, acc[1] * inv);
    o.y = pack2(acc[2] * inv, acc[3] * inv);
    o.z = pack2(acc[4] * inv, acc[5] * inv);
    o.w = pack2(acc[6] * inv, acc[7] * inv);
    *(uint4*)(out + (size_t)node * DIM + coff) = o;
}

// ---------------- m97-style 2-phase global_load_lds MFMA GEMM ----------------
// C[M,NCOLS] = relu(A[M,512] @ B + bias); A row-major bf16, Bt [NCOLS][512] bf16.
// 128x128 tile, BK=32, 4 waves, double-buffered LINEAR LDS [128][32] (16B/lane DMA).
// Grid: (col_blocks, row_blocks) with col fastest -> row-panel's col-blocks co-resident.
// OMODE: 0 = fp32 out, 1 = bf16 out.
template <int NCOLS, int OMODE>
__global__ __launch_bounds__(256) void k_ggemm(const ushort* __restrict__ A,
                                               const ushort* __restrict__ Bt,
                                               const float* __restrict__ bias,
                                               float* __restrict__ Cf,
                                               ushort* __restrict__ Cb, int M) {
    constexpr int K = 512;
    constexpr int NT = K / 32;
    __shared__ ushort As[2][128 * 32];
    __shared__ ushort Bs[2][128 * 32];
    const int tid = threadIdx.x;
    const int wid = tid >> 6, lane = tid & 63;
    const int wm = wid >> 1, wn = wid & 1;
    const int col0 = blockIdx.x * 128;
    const int row0 = blockIdx.y * 128;
    const int l15 = lane & 15, lk = (lane >> 4) * 8;

    // staging: each wave covers rows [wid*32, wid*32+32) of both tiles,
    // in 2 insts of 16 rows; lane l -> row +(l>>2), k-seg (l&3)*8 elems.
    const int sbase = wid * 32;
    const int lrow = lane >> 2;
    const int lseg = (lane & 3) * 8;

    auto stage = [&](int buf, int k0) {
#pragma unroll
        for (int j = 0; j < 2; j++) {
            const int r = sbase + j * 16;
            int gr = row0 + r + lrow;
            if (gr > M - 1) gr = M - 1;  // clamp; garbage rows masked at store
            GL2LDS(A + (size_t)gr * K + k0 + lseg, &As[buf][r * 32]);
            int gc = col0 + r + lrow;
            if (NCOLS % 128 != 0) {
                if (gc > NCOLS - 1) gc = NCOLS - 1;
            }
            GL2LDS(Bt + (size_t)gc * K + k0 + lseg, &Bs[buf][r * 32]);
        }
    };

    f32x4 acc[4][4] = {};
    stage(0, 0);
    __syncthreads();  // drains vmcnt(0): buf0 ready
    for (int t = 0; t < NT; ++t) {
        const int cur = t & 1;
        if (t + 1 < NT) stage(cur ^ 1, (t + 1) * 32);  // prefetch overlaps compute
        short8 a[4], b[4];
#pragma unroll
        for (int m = 0; m < 4; m++)
            a[m] = *(const short8*)(&As[cur][(wm * 64 + m * 16 + l15) * 32 + lk]);
#pragma unroll
        for (int n = 0; n < 4; n++)
            b[n] = *(const short8*)(&Bs[cur][(wn * 64 + n * 16 + l15) * 32 + lk]);
#pragma unroll
        for (int m = 0; m < 4; m++)
#pragma unroll
            for (int n = 0; n < 4; n++)
                acc[m][n] = __builtin_amdgcn_mfma_f32_16x16x32_bf16(a[m], b[n], acc[m][n], 0, 0, 0);
        __syncthreads();  // all reads of buf[cur] done; drains prefetch vmcnt
    }

    const int crow = row0 + wm * 64;
    const int ccol = col0 + wn * 64;
#pragma unroll
    for (int n = 0; n < 4; n++) {
        int c = ccol + n * 16 + l15;
        if (NCOLS % 128 != 0 && c >= NCOLS) continue;
        float bv = bias[c];
#pragma unroll
        for (int m = 0; m < 4; m++) {
#pragma unroll
            for (int i = 0; i < 4; i++) {
                int r = crow + m * 16 + (lane >> 4) * 4 + i;
                if (r >= M) continue;
                float v = fmaxf(acc[m][n][i] + bv, 0.0f);
                if (OMODE == 0) Cf[(size_t)r * NCOLS + c] = v;
                else Cb[(size_t)r * NCOLS + c] = f2bf(v);
            }
        }
    }
}

// ---------------- BN stats over N rows of hm[N,200] ----------------
__global__ void k_bnstat(const float* __restrict__ hm, float* __restrict__ gsum,
                         float* __restrict__ gsq) {
    int j = threadIdx.x;
    if (j >= MLPH) return;
    float s = 0.f, q = 0.f;
    for (int r = blockIdx.x; r < NN; r += gridDim.x) {
        float v = hm[(size_t)r * MLPH + j];
        s += v;
        q += v * v;
    }
    atomicAdd(&gsum[j], s);
    atomicAdd(&gsq[j], q);
}

__global__ void k_bnfin(const float* __restrict__ gsum, const float* __restrict__ gsq,
                        const float* __restrict__ gamma, const float* __restrict__ beta,
                        const float* __restrict__ Wo, const float* __restrict__ bo,
                        float* __restrict__ Wo2, float* __restrict__ bo2) {
    __shared__ float sh[MLPH];
    int j = threadIdx.x;
    if (j < MLPH) {
        float mean = gsum[j] / (float)NN;
        float var = gsq[j] / (float)NN - mean * mean;
        float scale = gamma[j] * rsqrtf(var + 1e-5f);
        float shift = beta[j] - mean * scale;
        sh[j] = shift;
        Wo2[j * 2 + 0] = scale * Wo[j * 2 + 0];
        Wo2[j * 2 + 1] = scale * Wo[j * 2 + 1];
    }
    __syncthreads();
    if (j < 2) {
        float acc = bo[j];
        for (int t = 0; t < MLPH; t++) acc += sh[t] * Wo[t * 2 + j];
        bo2[j] = acc;
    }
}

__global__ void k_out(const float* __restrict__ hm, const float* __restrict__ Wo2,
                      const float* __restrict__ bo2, float* __restrict__ out) {
    __shared__ float w[MLPH * 2];
    if (threadIdx.x < MLPH * 2) w[threadIdx.x] = Wo2[threadIdx.x];
    __syncthreads();
    int wid = (blockIdx.x * blockDim.x + threadIdx.x) >> 6;
    int lane = threadIdx.x & 63;
    if (wid >= NN) return;
    const float* row = hm + (size_t)wid * MLPH;
    float p0 = 0.f, p1 = 0.f;
    for (int j = lane; j < MLPH; j += 64) {
        float v = row[j];
        p0 += v * w[j * 2 + 0];
        p1 += v * w[j * 2 + 1];
    }
    for (int off = 32; off; off >>= 1) {
        p0 += __shfl_down(p0, off);
        p1 += __shfl_down(p1, off);
    }
    if (lane == 0) {
        out[wid * 2 + 0] = p0 + bo2[0];
        out[wid * 2 + 1] = p1 + bo2[1];
    }
}

extern "C" void kernel_launch(void* const* d_in, const int* in_sizes, int n_in,
                              void* d_out, int out_size, void* d_ws, size_t ws_size,
                              hipStream_t stream) {
    const float* features = (const float*)d_in[0];
    const int* src = (const int*)d_in[1];
    const int* dst = (const int*)d_in[2];
    const float* W1 = (const float*)d_in[3];
    const float* b1 = (const float*)d_in[4];
    const float* W2 = (const float*)d_in[5];
    const float* b2 = (const float*)d_in[6];
    const float* Wh = (const float*)d_in[7];
    const float* bh = (const float*)d_in[8];
    const float* gamma = (const float*)d_in[9];
    const float* beta = (const float*)d_in[10];
    const float* Wo = (const float*)d_in[11];
    const float* bo = (const float*)d_in[12];
    float* out = (float*)d_out;

    char* w = (char*)d_ws;
    auto alloc = [&](size_t bytes) -> void* {
        void* p = (void*)w;
        w += (bytes + 255) & ~(size_t)255;
        return p;
    };
    ushort* fb = (ushort*)alloc((size_t)NN * DIM * 2);   // features bf16; later h2 bf16
    ushort* ab = (ushort*)alloc((size_t)NN * DIM * 2);   // aggregation output bf16
    ushort* hb = (ushort*)alloc((size_t)NN * DIM * 2);   // h1 bf16
    float* hm = (float*)alloc((size_t)NN * MLPH * 4);    // MLP hidden fp32
    ushort* W1t = (ushort*)alloc((size_t)DIM * DIM * 2);
    ushort* W2t = (ushort*)alloc((size_t)DIM * DIM * 2);
    ushort* Wht = (ushort*)alloc((size_t)MLPH * DIM * 2);
    int* adj = (int*)alloc((size_t)NE * 4);
    int* counts = (int*)alloc((size_t)NN * 4);
    int* rowstart = (int*)alloc((size_t)(NN + 1) * 4);
    int* cursor = (int*)alloc((size_t)NN * 4);
    int* partial = (int*)alloc(256 * 4);
    float* gsum = (float*)alloc(MLPH * 4);
    float* gsq = (float*)alloc(MLPH * 4);
    float* Wo2 = (float*)alloc(MLPH * 2 * 4);
    float* bo2 = (float*)alloc(2 * 4);

    hipMemsetAsync(counts, 0, (size_t)NN * 4, stream);
    hipMemsetAsync(gsum, 0, MLPH * 4, stream);
    hipMemsetAsync(gsq, 0, MLPH * 4, stream);

    const int NB = (NN + 255) / 256;  // 196

    // CSR build (parallel scan)
    k_hist<<<(NE + 255) / 256, 256, 0, stream>>>(dst, counts);
    k_part<<<NB, 256, 0, stream>>>(counts, partial);
    k_scanp<<<1, 256, 0, stream>>>(partial, rowstart, NB);
    k_scan2<<<NB, 256, 0, stream>>>(counts, partial, rowstart, cursor);
    k_fill<<<(NE + 255) / 256, 256, 0, stream>>>(src, dst, cursor, adj);

    // conversions
    const int n4 = NN * DIM / 4;
    k_cvt<<<(n4 + 255) / 256, 256, 0, stream>>>(features, fb, n4);
    const int WT = 2 * 512 * 512 + MLPH * 512;
    k_wt3<<<(WT + 255) / 256, 256, 0, stream>>>(W1, W2, Wh, W1t, W2t, Wht);

    const int MB = (NN + 127) / 128;  // 391

    // layer 1
    k_agg_bf<<<(NN + 3) / 4, 256, 0, stream>>>(fb, rowstart, adj, ab);
    k_ggemm<DIM, 1><<<dim3(4, MB), 256, 0, stream>>>(ab, W1t, b1, nullptr, hb, NN);
    // layer 2 (h2 -> fb)
    k_agg_bf<<<(NN + 3) / 4, 256, 0, stream>>>(hb, rowstart, adj, ab);
    k_ggemm<DIM, 1><<<dim3(4, MB), 256, 0, stream>>>(ab, W2t, b2, nullptr, fb, NN);
    // MLP hidden: hm = relu(h2 @ Wh + bh), fp32 out
    k_ggemm<MLPH, 0><<<dim3(2, MB), 256, 0, stream>>>(fb, Wht, bh, hm, nullptr, NN);
    // BatchNorm stats + fold into Wo/bo
    k_bnstat<<<512, 256, 0, stream>>>(hm, gsum, gsq);
    k_bnfin<<<1, 256, 0, stream>>>(gsum, gsq, gamma, beta, Wo, bo, Wo2, bo2);
    // output
    k_out<<<(NN * 64 + 511) / 512, 512, 0, stream>>>(hm, Wo2, bo2, out);
}

// Round 10
// 595.551 us; speedup vs baseline: 1.0155x; 1.0155x over previous
//
#include <hip/hip_runtime.h>

#define NN 50000
#define NE 800000
#define DIM 512
#define MLPH 200

typedef __attribute__((ext_vector_type(8))) short short8;
typedef __attribute__((ext_vector_type(4))) float f32x4;
typedef __attribute__((ext_vector_type(4))) unsigned int u32x4;

// async global->LDS, 16B per lane, wave-uniform LDS base (m97 pattern)
#define GL2LDS(g, l)                                                     \
    __builtin_amdgcn_global_load_lds(                                    \
        (const __attribute__((address_space(1))) unsigned int*)(g),      \
        (__attribute__((address_space(3))) unsigned int*)(l), 16, 0, 0)

__device__ inline unsigned short f2bf(float f) {
    unsigned int u = __float_as_uint(f);
    unsigned int r = (u + 0x7fffu + ((u >> 16) & 1u)) >> 16;
    return (unsigned short)r;
}
__device__ inline float bflo(unsigned u) { return __uint_as_float(u << 16); }
__device__ inline float bfhi(unsigned u) { return __uint_as_float(u & 0xffff0000u); }
__device__ inline unsigned pack2(float a, float b) {
    return (unsigned)f2bf(a) | ((unsigned)f2bf(b) << 16);
}

// ---------------- CSR build ----------------
__global__ void k_hist(const int* __restrict__ dst, int* __restrict__ counts) {
    int e = blockIdx.x * blockDim.x + threadIdx.x;
    if (e < NE) atomicAdd(&counts[dst[e]], 1);
}

__global__ void k_part(const int* __restrict__ counts, int* __restrict__ partial) {
    int t = threadIdx.x;
    int i = blockIdx.x * 256 + t;
    int x = (i < NN) ? counts[i] : 0;
#pragma unroll
    for (int off = 32; off; off >>= 1) x += __shfl_down(x, off);
    __shared__ int ws[4];
    if ((t & 63) == 0) ws[t >> 6] = x;
    __syncthreads();
    if (t == 0) partial[blockIdx.x] = ws[0] + ws[1] + ws[2] + ws[3];
}

__global__ void k_scanp(int* __restrict__ partial, int* __restrict__ rowstart, int nb) {
    __shared__ int ws[4];
    int t = threadIdx.x;
    int x = (t < nb) ? partial[t] : 0;
    int v = x;
#pragma unroll
    for (int off = 1; off < 64; off <<= 1) {
        int u = __shfl_up(v, off);
        if ((t & 63) >= off) v += u;
    }
    if ((t & 63) == 63) ws[t >> 6] = v;
    __syncthreads();
    int add = 0;
#pragma unroll
    for (int w = 0; w < 4; w++)
        if (w < (t >> 6)) add += ws[w];
    if (t < nb) partial[t] = v - x + add;  // exclusive
    if (t == 255) rowstart[NN] = v + add;  // total == NE
}

__global__ void k_scan2(const int* __restrict__ counts, const int* __restrict__ pexcl,
                        int* __restrict__ rowstart, int* __restrict__ cursor) {
    __shared__ int ws[4];
    int t = threadIdx.x;
    int i = blockIdx.x * 256 + t;
    int x = (i < NN) ? counts[i] : 0;
    int v = x;
#pragma unroll
    for (int off = 1; off < 64; off <<= 1) {
        int u = __shfl_up(v, off);
        if ((t & 63) >= off) v += u;
    }
    if ((t & 63) == 63) ws[t >> 6] = v;
    __syncthreads();
    int add = 0;
#pragma unroll
    for (int w = 0; w < 4; w++)
        if (w < (t >> 6)) add += ws[w];
    if (i < NN) {
        int r = pexcl[blockIdx.x] + v - x + add;
        rowstart[i] = r;
        cursor[i] = r;
    }
}

__global__ void k_fill(const int* __restrict__ src, const int* __restrict__ dst,
                       int* __restrict__ cursor, int* __restrict__ adj) {
    int e = blockIdx.x * blockDim.x + threadIdx.x;
    if (e < NE) {
        int p = atomicAdd(&cursor[dst[e]], 1);
        adj[p] = src[e];
    }
}

// ---------------- fp32 -> bf16 conversion (features, row-major) ----------------
__global__ void k_cvt(const float* __restrict__ in, ushort* __restrict__ out, int n4) {
    int i = blockIdx.x * blockDim.x + threadIdx.x;
    if (i >= n4) return;
    float4 v = *(const float4*)(in + (size_t)i * 4);
    ushort2 a{f2bf(v.x), f2bf(v.y)}, b{f2bf(v.z), f2bf(v.w)};
    *(ushort2*)(out + (size_t)i * 4) = a;
    *(ushort2*)(out + (size_t)i * 4 + 2) = b;
}

// ---------------- all three weight transposes in one kernel ----------------
__global__ void k_wt3(const float* __restrict__ W1, const float* __restrict__ W2,
                      const float* __restrict__ Wh, ushort* __restrict__ W1t,
                      ushort* __restrict__ W2t, ushort* __restrict__ Wht) {
    int i = blockIdx.x * 256 + threadIdx.x;
    const int S1 = 512 * 512, S2 = 2 * 512 * 512, S3 = 2 * 512 * 512 + MLPH * 512;
    if (i < S1) {
        int n = i >> 9, k = i & 511;
        W1t[i] = f2bf(W1[(size_t)k * 512 + n]);
    } else if (i < S2) {
        int j = i - S1, n = j >> 9, k = j & 511;
        W2t[j] = f2bf(W2[(size_t)k * 512 + n]);
    } else if (i < S3) {
        int j = i - S2, n = j >> 9, k = j & 511;
        Wht[j] = f2bf(Wh[(size_t)k * MLPH + n]);
    }
}

// ---------------- aggregation (row-major bf16, fp32 accum): (sum_nbr + 2*self)/(deg+2) ----------------
// Streaming traffic (adj reads, out writes) is non-temporal so it doesn't evict
// gather lines from L2; gather loads stay temporal (they ARE the reuse).
__device__ inline void addrow(float* acc, uint4 v) {
    acc[0] += bflo(v.x); acc[1] += bfhi(v.x);
    acc[2] += bflo(v.y); acc[3] += bfhi(v.y);
    acc[4] += bflo(v.z); acc[5] += bfhi(v.z);
    acc[6] += bflo(v.w); acc[7] += bfhi(v.w);
}

__global__ __launch_bounds__(256) void k_agg_bf(const ushort* __restrict__ h,
                                                const int* __restrict__ rowstart,
                                                const int* __restrict__ adj,
                                                ushort* __restrict__ out) {
    int node = blockIdx.x * 4 + (threadIdx.x >> 6);
    int lane = threadIdx.x & 63;
    if (node >= NN) return;
    int s = rowstart[node], e = rowstart[node + 1];
    const size_t coff = (size_t)lane * 8;
    float acc[8];
    {
        uint4 v = *(const uint4*)(h + (size_t)node * DIM + coff);
        acc[0] = 2.f * bflo(v.x); acc[1] = 2.f * bfhi(v.x);
        acc[2] = 2.f * bflo(v.y); acc[3] = 2.f * bfhi(v.y);
        acc[4] = 2.f * bflo(v.z); acc[5] = 2.f * bfhi(v.z);
        acc[6] = 2.f * bflo(v.w); acc[7] = 2.f * bfhi(v.w);
    }
    int i = s;
    int e4 = s + ((e - s) & ~3);
    for (; i < e4; i += 4) {
        int n0 = __builtin_nontemporal_load(adj + i);
        int n1 = __builtin_nontemporal_load(adj + i + 1);
        int n2 = __builtin_nontemporal_load(adj + i + 2);
        int n3 = __builtin_nontemporal_load(adj + i + 3);
        uint4 v0 = *(const uint4*)(h + (size_t)n0 * DIM + coff);
        uint4 v1 = *(const uint4*)(h + (size_t)n1 * DIM + coff);
        uint4 v2 = *(const uint4*)(h + (size_t)n2 * DIM + coff);
        uint4 v3 = *(const uint4*)(h + (size_t)n3 * DIM + coff);
        addrow(acc, v0);
        addrow(acc, v1);
        addrow(acc, v2);
        addrow(acc, v3);
    }
    for (; i < e; i++) {
        int nbr = __builtin_nontemporal_load(adj + i);
        uint4 v = *(const uint4*)(h + (size_t)nbr * DIM + coff);
        addrow(acc, v);
    }
    float inv = 1.0f / (float)(e - s + 2);
    u32x4 o;
    o.x = pack2(acc[0] * inv, acc[1] * inv);
    o.y = pack2(acc[2] * inv, acc[3] * inv);
    o.z = pack2(acc[4] * inv, acc[5] * inv);
    o.w = pack2(acc[6] * inv, acc[7] * inv);
    __builtin_nontemporal_store(o, (u32x4*)(out + (size_t)node * DIM + coff));
}

// ---------------- 2-phase global_load_lds MFMA GEMM, 256x128 tile ----------------
// C[M,NCOLS] = relu(A[M,512] @ B + bias); A row-major bf16, Bt [NCOLS][512] bf16.
// 512 threads / 8 waves (4 row x 2 col), BK=32, double-buffered LINEAR LDS (48KB).
// 1D grid with bijective XCD swizzle (nwg % 8 == 0); col-fastest inside each
// XCD chunk so a row-panel's col-blocks share the A panel in one XCD's L2.
// OMODE: 0 = fp32 out, 1 = bf16 out.
template <int NCOLS, int OMODE>
__global__ __launch_bounds__(512) void k_ggemm(const ushort* __restrict__ A,
                                               const ushort* __restrict__ Bt,
                                               const float* __restrict__ bias,
                                               float* __restrict__ Cf,
                                               ushort* __restrict__ Cb, int M) {
    constexpr int K = 512;
    constexpr int NT = K / 32;
    constexpr int NC = (NCOLS + 127) / 128;  // col blocks
    __shared__ ushort As[2][256 * 32];  // 32 KB
    __shared__ ushort Bs[2][128 * 32];  // 16 KB
    const int tid = threadIdx.x;
    const int wid = tid >> 6, lane = tid & 63;
    const int wm = wid >> 1, wn = wid & 1;

    // XCD-aware bijective swizzle (gridDim.x % 8 == 0)
    const int cpx = gridDim.x >> 3;
    const int wg = (blockIdx.x & 7) * cpx + (blockIdx.x >> 3);
    const int col0 = (wg % NC) * 128;
    const int row0 = (wg / NC) * 256;

    const int l15 = lane & 15, lk = (lane >> 4) * 8;
    const int lrow = lane >> 2;         // 0..15
    const int lseg = (lane & 3) * 8;    // k-seg in elems

    auto stage = [&](int buf, int k0) {
#pragma unroll
        for (int j = 0; j < 2; j++) {
            const int r = wid * 16 + j * 128;  // wave-uniform
            int gr = row0 + r + lrow;
            if (gr > M - 1) gr = M - 1;  // clamp; garbage rows masked at store
            GL2LDS(A + (size_t)gr * K + k0 + lseg, &As[buf][r * 32]);
        }
        const int rb = wid * 16;  // wave-uniform
        int gc = col0 + rb + lrow;
        if (NCOLS % 128 != 0) {
            if (gc > NCOLS - 1) gc = NCOLS - 1;
        }
        GL2LDS(Bt + (size_t)gc * K + k0 + lseg, &Bs[buf][rb * 32]);
    };

    f32x4 acc[4][4] = {};
    stage(0, 0);
    __syncthreads();  // drains vmcnt(0): buf0 ready
    for (int t = 0; t < NT; ++t) {
        const int cur = t & 1;
        if (t + 1 < NT) stage(cur ^ 1, (t + 1) * 32);  // prefetch overlaps compute
        short8 a[4], b[4];
#pragma unroll
        for (int m = 0; m < 4; m++)
            a[m] = *(const short8*)(&As[cur][(wm * 64 + m * 16 + l15) * 32 + lk]);
#pragma unroll
        for (int n = 0; n < 4; n++)
            b[n] = *(const short8*)(&Bs[cur][(wn * 64 + n * 16 + l15) * 32 + lk]);
#pragma unroll
        for (int m = 0; m < 4; m++)
#pragma unroll
            for (int n = 0; n < 4; n++)
                acc[m][n] = __builtin_amdgcn_mfma_f32_16x16x32_bf16(a[m], b[n], acc[m][n], 0, 0, 0);
        __syncthreads();  // all reads of buf[cur] done; drains prefetch vmcnt
    }

    const int crow = row0 + wm * 64;
    const int ccol = col0 + wn * 64;
#pragma unroll
    for (int n = 0; n < 4; n++) {
        int c = ccol + n * 16 + l15;
        if (NCOLS % 128 != 0 && c >= NCOLS) continue;
        float bv = bias[c];
#pragma unroll
        for (int m = 0; m < 4; m++) {
#pragma unroll
            for (int i = 0; i < 4; i++) {
                int r = crow + m * 16 + (lane >> 4) * 4 + i;
                if (r >= M) continue;
                float v = fmaxf(acc[m][n][i] + bv, 0.0f);
                if (OMODE == 0) Cf[(size_t)r * NCOLS + c] = v;
                else Cb[(size_t)r * NCOLS + c] = f2bf(v);
            }
        }
    }
}

// ---------------- BN stats over N rows of hm[N,200] ----------------
__global__ void k_bnstat(const float* __restrict__ hm, float* __restrict__ gsum,
                         float* __restrict__ gsq) {
    int j = threadIdx.x;
    if (j >= MLPH) return;
    float s = 0.f, q = 0.f;
    for (int r = blockIdx.x; r < NN; r += gridDim.x) {
        float v = hm[(size_t)r * MLPH + j];
        s += v;
        q += v * v;
    }
    atomicAdd(&gsum[j], s);
    atomicAdd(&gsq[j], q);
}

__global__ void k_bnfin(const float* __restrict__ gsum, const float* __restrict__ gsq,
                        const float* __restrict__ gamma, const float* __restrict__ beta,
                        const float* __restrict__ Wo, const float* __restrict__ bo,
                        float* __restrict__ Wo2, float* __restrict__ bo2) {
    __shared__ float sh[MLPH];
    int j = threadIdx.x;
    if (j < MLPH) {
        float mean = gsum[j] / (float)NN;
        float var = gsq[j] / (float)NN - mean * mean;
        float scale = gamma[j] * rsqrtf(var + 1e-5f);
        float shift = beta[j] - mean * scale;
        sh[j] = shift;
        Wo2[j * 2 + 0] = scale * Wo[j * 2 + 0];
        Wo2[j * 2 + 1] = scale * Wo[j * 2 + 1];
    }
    __syncthreads();
    if (j < 2) {
        float acc = bo[j];
        for (int t = 0; t < MLPH; t++) acc += sh[t] * Wo[t * 2 + j];
        bo2[j] = acc;
    }
}

__global__ void k_out(const float* __restrict__ hm, const float* __restrict__ Wo2,
                      const float* __restrict__ bo2, float* __restrict__ out) {
    __shared__ float w[MLPH * 2];
    if (threadIdx.x < MLPH * 2) w[threadIdx.x] = Wo2[threadIdx.x];
    __syncthreads();
    int wid = (blockIdx.x * blockDim.x + threadIdx.x) >> 6;
    int lane = threadIdx.x & 63;
    if (wid >= NN) return;
    const float* row = hm + (size_t)wid * MLPH;
    float p0 = 0.f, p1 = 0.f;
    for (int j = lane; j < MLPH; j += 64) {
        float v = row[j];
        p0 += v * w[j * 2 + 0];
        p1 += v * w[j * 2 + 1];
    }
    for (int off = 32; off; off >>= 1) {
        p0 += __shfl_down(p0, off);
        p1 += __shfl_down(p1, off);
    }
    if (lane == 0) {
        out[wid * 2 + 0] = p0 + bo2[0];
        out[wid * 2 + 1] = p1 + bo2[1];
    }
}

extern "C" void kernel_launch(void* const* d_in, const int* in_sizes, int n_in,
                              void* d_out, int out_size, void* d_ws, size_t ws_size,
                              hipStream_t stream) {
    const float* features = (const float*)d_in[0];
    const int* src = (const int*)d_in[1];
    const int* dst = (const int*)d_in[2];
    const float* W1 = (const float*)d_in[3];
    const float* b1 = (const float*)d_in[4];
    const float* W2 = (const float*)d_in[5];
    const float* b2 = (const float*)d_in[6];
    const float* Wh = (const float*)d_in[7];
    const float* bh = (const float*)d_in[8];
    const float* gamma = (const float*)d_in[9];
    const float* beta = (const float*)d_in[10];
    const float* Wo = (const float*)d_in[11];
    const float* bo = (const float*)d_in[12];
    float* out = (float*)d_out;

    char* w = (char*)d_ws;
    auto alloc = [&](size_t bytes) -> void* {
        void* p = (void*)w;
        w += (bytes + 255) & ~(size_t)255;
        return p;
    };
    ushort* fb = (ushort*)alloc((size_t)NN * DIM * 2);   // features bf16; later h2 bf16
    ushort* ab = (ushort*)alloc((size_t)NN * DIM * 2);   // aggregation output bf16
    ushort* hb = (ushort*)alloc((size_t)NN * DIM * 2);   // h1 bf16
    float* hm = (float*)alloc((size_t)NN * MLPH * 4);    // MLP hidden fp32
    ushort* W1t = (ushort*)alloc((size_t)DIM * DIM * 2);
    ushort* W2t = (ushort*)alloc((size_t)DIM * DIM * 2);
    ushort* Wht = (ushort*)alloc((size_t)MLPH * DIM * 2);
    int* adj = (int*)alloc((size_t)NE * 4);
    int* counts = (int*)alloc((size_t)NN * 4);
    int* rowstart = (int*)alloc((size_t)(NN + 1) * 4);
    int* cursor = (int*)alloc((size_t)NN * 4);
    int* partial = (int*)alloc(256 * 4);
    float* gsum = (float*)alloc(MLPH * 4);
    float* gsq = (float*)alloc(MLPH * 4);
    float* Wo2 = (float*)alloc(MLPH * 2 * 4);
    float* bo2 = (float*)alloc(2 * 4);

    hipMemsetAsync(counts, 0, (size_t)NN * 4, stream);
    hipMemsetAsync(gsum, 0, MLPH * 4, stream);
    hipMemsetAsync(gsq, 0, MLPH * 4, stream);

    const int NB = (NN + 255) / 256;  // 196

    // CSR build (parallel scan)
    k_hist<<<(NE + 255) / 256, 256, 0, stream>>>(dst, counts);
    k_part<<<NB, 256, 0, stream>>>(counts, partial);
    k_scanp<<<1, 256, 0, stream>>>(partial, rowstart, NB);
    k_scan2<<<NB, 256, 0, stream>>>(counts, partial, rowstart, cursor);
    k_fill<<<(NE + 255) / 256, 256, 0, stream>>>(src, dst, cursor, adj);

    // conversions
    const int n4 = NN * DIM / 4;
    k_cvt<<<(n4 + 255) / 256, 256, 0, stream>>>(features, fb, n4);
    const int WT = 2 * 512 * 512 + MLPH * 512;
    k_wt3<<<(WT + 255) / 256, 256, 0, stream>>>(W1, W2, Wh, W1t, W2t, Wht);

    const int MBr = (NN + 255) / 256;  // 196 row-panels of 256
    const int G512 = 4 * MBr;          // 784 blocks (784 % 8 == 0)
    const int G200 = 2 * MBr;          // 392 blocks (392 % 8 == 0)

    // layer 1
    k_agg_bf<<<(NN + 3) / 4, 256, 0, stream>>>(fb, rowstart, adj, ab);
    k_ggemm<DIM, 1><<<G512, 512, 0, stream>>>(ab, W1t, b1, nullptr, hb, NN);
    // layer 2 (h2 -> fb)
    k_agg_bf<<<(NN + 3) / 4, 256, 0, stream>>>(hb, rowstart, adj, ab);
    k_ggemm<DIM, 1><<<G512, 512, 0, stream>>>(ab, W2t, b2, nullptr, fb, NN);
    // MLP hidden: hm = relu(h2 @ Wh + bh), fp32 out
    k_ggemm<MLPH, 0><<<G200, 512, 0, stream>>>(fb, Wht, bh, hm, nullptr, NN);
    // BatchNorm stats + fold into Wo/bo
    k_bnstat<<<512, 256, 0, stream>>>(hm, gsum, gsq);
    k_bnfin<<<1, 256, 0, stream>>>(gsum, gsq, gamma, beta, Wo, bo, Wo2, bo2);
    // output
    k_out<<<(NN * 64 + 511) / 512, 512, 0, stream>>>(hm, Wo2, bo2, out);
}

// Round 11
// 587.699 us; speedup vs baseline: 1.0291x; 1.0134x over previous
//
#include <hip/hip_runtime.h>

#define NN 50000
#define NE 800000
#define DIM 512
#define MLPH 200

typedef __attribute__((ext_vector_type(8))) short short8;
typedef __attribute__((ext_vector_type(4))) float f32x4;
typedef __attribute__((ext_vector_type(4))) unsigned int u32x4;

// async global->LDS, 16B per lane, wave-uniform LDS base (m97 pattern)
#define GL2LDS(g, l)                                                     \
    __builtin_amdgcn_global_load_lds(                                    \
        (const __attribute__((address_space(1))) unsigned int*)(g),      \
        (__attribute__((address_space(3))) unsigned int*)(l), 16, 0, 0)

__device__ inline unsigned short f2bf(float f) {
    unsigned int u = __float_as_uint(f);
    unsigned int r = (u + 0x7fffu + ((u >> 16) & 1u)) >> 16;
    return (unsigned short)r;
}
__device__ inline float bflo(unsigned u) { return __uint_as_float(u << 16); }
__device__ inline float bfhi(unsigned u) { return __uint_as_float(u & 0xffff0000u); }
__device__ inline float bf1(unsigned short u) { return __uint_as_float((unsigned)u << 16); }
__device__ inline unsigned pack2(float a, float b) {
    return (unsigned)f2bf(a) | ((unsigned)f2bf(b) << 16);
}

// ---------------- CSR build ----------------
__global__ void k_hist(const int* __restrict__ dst, int* __restrict__ counts) {
    int e = blockIdx.x * blockDim.x + threadIdx.x;
    if (e < NE) atomicAdd(&counts[dst[e]], 1);
}

__global__ void k_part(const int* __restrict__ counts, int* __restrict__ partial) {
    int t = threadIdx.x;
    int i = blockIdx.x * 256 + t;
    int x = (i < NN) ? counts[i] : 0;
#pragma unroll
    for (int off = 32; off; off >>= 1) x += __shfl_down(x, off);
    __shared__ int ws[4];
    if ((t & 63) == 0) ws[t >> 6] = x;
    __syncthreads();
    if (t == 0) partial[blockIdx.x] = ws[0] + ws[1] + ws[2] + ws[3];
}

__global__ void k_scanp(int* __restrict__ partial, int* __restrict__ rowstart, int nb) {
    __shared__ int ws[4];
    int t = threadIdx.x;
    int x = (t < nb) ? partial[t] : 0;
    int v = x;
#pragma unroll
    for (int off = 1; off < 64; off <<= 1) {
        int u = __shfl_up(v, off);
        if ((t & 63) >= off) v += u;
    }
    if ((t & 63) == 63) ws[t >> 6] = v;
    __syncthreads();
    int add = 0;
#pragma unroll
    for (int w = 0; w < 4; w++)
        if (w < (t >> 6)) add += ws[w];
    if (t < nb) partial[t] = v - x + add;  // exclusive
    if (t == 255) rowstart[NN] = v + add;  // total == NE
}

__global__ void k_scan2(const int* __restrict__ counts, const int* __restrict__ pexcl,
                        int* __restrict__ rowstart, int* __restrict__ cursor) {
    __shared__ int ws[4];
    int t = threadIdx.x;
    int i = blockIdx.x * 256 + t;
    int x = (i < NN) ? counts[i] : 0;
    int v = x;
#pragma unroll
    for (int off = 1; off < 64; off <<= 1) {
        int u = __shfl_up(v, off);
        if ((t & 63) >= off) v += u;
    }
    if ((t & 63) == 63) ws[t >> 6] = v;
    __syncthreads();
    int add = 0;
#pragma unroll
    for (int w = 0; w < 4; w++)
        if (w < (t >> 6)) add += ws[w];
    if (i < NN) {
        int r = pexcl[blockIdx.x] + v - x + add;
        rowstart[i] = r;
        cursor[i] = r;
    }
}

__global__ void k_fill(const int* __restrict__ src, const int* __restrict__ dst,
                       int* __restrict__ cursor, int* __restrict__ adj) {
    int e = blockIdx.x * blockDim.x + threadIdx.x;
    if (e < NE) {
        int p = atomicAdd(&cursor[dst[e]], 1);
        adj[p] = src[e];
    }
}

// ---------------- fp32 -> bf16 conversion (features, row-major) ----------------
__global__ void k_cvt(const float* __restrict__ in, ushort* __restrict__ out, int n4) {
    int i = blockIdx.x * blockDim.x + threadIdx.x;
    if (i >= n4) return;
    float4 v = *(const float4*)(in + (size_t)i * 4);
    ushort2 a{f2bf(v.x), f2bf(v.y)}, b{f2bf(v.z), f2bf(v.w)};
    *(ushort2*)(out + (size_t)i * 4) = a;
    *(ushort2*)(out + (size_t)i * 4 + 2) = b;
}

// ---------------- all three weight transposes in one kernel ----------------
__global__ void k_wt3(const float* __restrict__ W1, const float* __restrict__ W2,
                      const float* __restrict__ Wh, ushort* __restrict__ W1t,
                      ushort* __restrict__ W2t, ushort* __restrict__ Wht) {
    int i = blockIdx.x * 256 + threadIdx.x;
    const int S1 = 512 * 512, S2 = 2 * 512 * 512, S3 = 2 * 512 * 512 + MLPH * 512;
    if (i < S1) {
        int n = i >> 9, k = i & 511;
        W1t[i] = f2bf(W1[(size_t)k * 512 + n]);
    } else if (i < S2) {
        int j = i - S1, n = j >> 9, k = j & 511;
        W2t[j] = f2bf(W2[(size_t)k * 512 + n]);
    } else if (i < S3) {
        int j = i - S2, n = j >> 9, k = j & 511;
        Wht[j] = f2bf(Wh[(size_t)k * MLPH + n]);
    }
}

// ---------------- aggregation (row-major bf16, fp32 accum): (sum_nbr + 2*self)/(deg+2) ----------------
__device__ inline void addrow(float* acc, uint4 v) {
    acc[0] += bflo(v.x); acc[1] += bfhi(v.x);
    acc[2] += bflo(v.y); acc[3] += bfhi(v.y);
    acc[4] += bflo(v.z); acc[5] += bfhi(v.z);
    acc[6] += bflo(v.w); acc[7] += bfhi(v.w);
}

__global__ __launch_bounds__(256) void k_agg_bf(const ushort* __restrict__ h,
                                                const int* __restrict__ rowstart,
                                                const int* __restrict__ adj,
                                                ushort* __restrict__ out) {
    int node = blockIdx.x * 4 + (threadIdx.x >> 6);
    int lane = threadIdx.x & 63;
    if (node >= NN) return;
    int s = rowstart[node], e = rowstart[node + 1];
    const size_t coff = (size_t)lane * 8;
    float acc[8];
    {
        uint4 v = *(const uint4*)(h + (size_t)node * DIM + coff);
        acc[0] = 2.f * bflo(v.x); acc[1] = 2.f * bfhi(v.x);
        acc[2] = 2.f * bflo(v.y); acc[3] = 2.f * bfhi(v.y);
        acc[4] = 2.f * bflo(v.z); acc[5] = 2.f * bfhi(v.z);
        acc[6] = 2.f * bflo(v.w); acc[7] = 2.f * bfhi(v.w);
    }
    int i = s;
    int e4 = s + ((e - s) & ~3);
    for (; i < e4; i += 4) {
        int n0 = adj[i], n1 = adj[i + 1], n2 = adj[i + 2], n3 = adj[i + 3];
        uint4 v0 = *(const uint4*)(h + (size_t)n0 * DIM + coff);
        uint4 v1 = *(const uint4*)(h + (size_t)n1 * DIM + coff);
        uint4 v2 = *(const uint4*)(h + (size_t)n2 * DIM + coff);
        uint4 v3 = *(const uint4*)(h + (size_t)n3 * DIM + coff);
        addrow(acc, v0);
        addrow(acc, v1);
        addrow(acc, v2);
        addrow(acc, v3);
    }
    for (; i < e; i++) {
        int nbr = adj[i];
        uint4 v = *(const uint4*)(h + (size_t)nbr * DIM + coff);
        addrow(acc, v);
    }
    float inv = 1.0f / (float)(e - s + 2);
    u32x4 o;
    o.x = pack2(acc[0] * inv, acc[1] * inv);
    o.y = pack2(acc[2] * inv, acc[3] * inv);
    o.z = pack2(acc[4] * inv, acc[5] * inv);
    o.w = pack2(acc[6] * inv, acc[7] * inv);
    __builtin_nontemporal_store(o, (u32x4*)(out + (size_t)node * DIM + coff));
}

// ---------------- 3-buffer counted-vmcnt global_load_lds MFMA GEMM, 256x128 tile ----------------
// C[M,NCOLS] = relu(A[M,512] @ B + bias); A row-major bf16, Bt [NCOLS][512] bf16.
// 512 threads / 8 waves (4 row x 2 col), BK=32, TRIPLE-buffered linear LDS (72KB).
// Per K-step: stage(t+2) || ds_read+MFMA(t) -> s_waitcnt vmcnt(3) -> s_barrier.
// Each stage = exactly 3 global_load_lds per wave, so vmcnt(3) proves stage(t+1)
// landed while stage(t+2)'s 3 loads stay in flight ACROSS the barrier (T3/T4).
// OMODE: 0 = fp32 out, 1 = bf16 out.
template <int NCOLS, int OMODE>
__global__ __launch_bounds__(512) void k_ggemm(const ushort* __restrict__ A,
                                               const ushort* __restrict__ Bt,
                                               const float* __restrict__ bias,
                                               float* __restrict__ Cf,
                                               ushort* __restrict__ Cb, int M) {
    constexpr int K = 512;
    constexpr int NT = K / 32;               // 16 K-steps
    constexpr int NC = (NCOLS + 127) / 128;  // col blocks
    __shared__ ushort As[3][256 * 32];  // 48 KB
    __shared__ ushort Bs[3][128 * 32];  // 24 KB
    const int tid = threadIdx.x;
    const int wid = tid >> 6, lane = tid & 63;
    const int wm = wid >> 1, wn = wid & 1;

    // XCD-aware bijective swizzle (gridDim.x % 8 == 0)
    const int cpx = gridDim.x >> 3;
    const int wg = (blockIdx.x & 7) * cpx + (blockIdx.x >> 3);
    const int col0 = (wg % NC) * 128;
    const int row0 = (wg / NC) * 256;

    const int l15 = lane & 15, lk = (lane >> 4) * 8;
    const int lrow = lane >> 2;       // 0..15
    const int lseg = (lane & 3) * 8;  // k-seg in elems

    auto stage = [&](int buf, int k0) {
#pragma unroll
        for (int j = 0; j < 2; j++) {
            const int r = wid * 16 + j * 128;  // wave-uniform
            int gr = row0 + r + lrow;
            if (gr > M - 1) gr = M - 1;  // clamp; garbage rows masked at store
            GL2LDS(A + (size_t)gr * K + k0 + lseg, &As[buf][r * 32]);
        }
        const int rb = wid * 16;  // wave-uniform
        int gc = col0 + rb + lrow;
        if (NCOLS % 128 != 0) {
            if (gc > NCOLS - 1) gc = NCOLS - 1;
        }
        GL2LDS(Bt + (size_t)gc * K + k0 + lseg, &Bs[buf][rb * 32]);
    };

    f32x4 acc[4][4] = {};
    // prologue: 2 stages in flight; wait oldest (buf0) before first read
    stage(0, 0);
    stage(1, 32);
    asm volatile("s_waitcnt vmcnt(3)" ::: "memory");
    __builtin_amdgcn_s_barrier();

    for (int t = 0; t < NT; ++t) {
        const int cur = t % 3;
        if (t + 2 < NT) stage((t + 2) % 3, (t + 2) * 32);  // overwrites buf (t-1)%3
        short8 a[4], b[4];
#pragma unroll
        for (int m = 0; m < 4; m++)
            a[m] = *(const short8*)(&As[cur][(wm * 64 + m * 16 + l15) * 32 + lk]);
#pragma unroll
        for (int n = 0; n < 4; n++)
            b[n] = *(const short8*)(&Bs[cur][(wn * 64 + n * 16 + l15) * 32 + lk]);
#pragma unroll
        for (int m = 0; m < 4; m++)
#pragma unroll
            for (int n = 0; n < 4; n++)
                acc[m][n] = __builtin_amdgcn_mfma_f32_16x16x32_bf16(a[m], b[n], acc[m][n], 0, 0, 0);
        if (t + 2 < NT) {
            // stage(t+1) done (<=3 newest outstanding = stage(t+2)); prefetch crosses barrier
            asm volatile("s_waitcnt vmcnt(3)" ::: "memory");
            __builtin_amdgcn_s_barrier();
        } else if (t + 1 < NT) {
            asm volatile("s_waitcnt vmcnt(0)" ::: "memory");
            __builtin_amdgcn_s_barrier();
        }
    }

    const int crow = row0 + wm * 64;
    const int ccol = col0 + wn * 64;
#pragma unroll
    for (int n = 0; n < 4; n++) {
        int c = ccol + n * 16 + l15;
        if (NCOLS % 128 != 0 && c >= NCOLS) continue;
        float bv = bias[c];
#pragma unroll
        for (int m = 0; m < 4; m++) {
#pragma unroll
            for (int i = 0; i < 4; i++) {
                int r = crow + m * 16 + (lane >> 4) * 4 + i;
                if (r >= M) continue;
                float v = fmaxf(acc[m][n][i] + bv, 0.0f);
                if (OMODE == 0) Cf[(size_t)r * NCOLS + c] = v;
                else Cb[(size_t)r * NCOLS + c] = f2bf(v);
            }
        }
    }
}

// ---------------- BN stats over N rows of hm[N,200] (bf16 in, fp32 accum) ----------------
__global__ void k_bnstat(const ushort* __restrict__ hm, float* __restrict__ gsum,
                         float* __restrict__ gsq) {
    int j = threadIdx.x;
    if (j >= MLPH) return;
    float s = 0.f, q = 0.f;
    for (int r = blockIdx.x; r < NN; r += gridDim.x) {
        float v = bf1(hm[(size_t)r * MLPH + j]);
        s += v;
        q += v * v;
    }
    atomicAdd(&gsum[j], s);
    atomicAdd(&gsq[j], q);
}

__global__ void k_bnfin(const float* __restrict__ gsum, const float* __restrict__ gsq,
                        const float* __restrict__ gamma, const float* __restrict__ beta,
                        const float* __restrict__ Wo, const float* __restrict__ bo,
                        float* __restrict__ Wo2, float* __restrict__ bo2) {
    __shared__ float sh[MLPH];
    int j = threadIdx.x;
    if (j < MLPH) {
        float mean = gsum[j] / (float)NN;
        float var = gsq[j] / (float)NN - mean * mean;
        float scale = gamma[j] * rsqrtf(var + 1e-5f);
        float shift = beta[j] - mean * scale;
        sh[j] = shift;
        Wo2[j * 2 + 0] = scale * Wo[j * 2 + 0];
        Wo2[j * 2 + 1] = scale * Wo[j * 2 + 1];
    }
    __syncthreads();
    if (j < 2) {
        float acc = bo[j];
        for (int t = 0; t < MLPH; t++) acc += sh[t] * Wo[t * 2 + j];
        bo2[j] = acc;
    }
}

__global__ void k_out(const ushort* __restrict__ hm, const float* __restrict__ Wo2,
                      const float* __restrict__ bo2, float* __restrict__ out) {
    __shared__ float w[MLPH * 2];
    if (threadIdx.x < MLPH * 2) w[threadIdx.x] = Wo2[threadIdx.x];
    __syncthreads();
    int wid = (blockIdx.x * blockDim.x + threadIdx.x) >> 6;
    int lane = threadIdx.x & 63;
    if (wid >= NN) return;
    const ushort* row = hm + (size_t)wid * MLPH;
    float p0 = 0.f, p1 = 0.f;
    for (int j = lane; j < MLPH; j += 64) {
        float v = bf1(row[j]);
        p0 += v * w[j * 2 + 0];
        p1 += v * w[j * 2 + 1];
    }
    for (int off = 32; off; off >>= 1) {
        p0 += __shfl_down(p0, off);
        p1 += __shfl_down(p1, off);
    }
    if (lane == 0) {
        out[wid * 2 + 0] = p0 + bo2[0];
        out[wid * 2 + 1] = p1 + bo2[1];
    }
}

extern "C" void kernel_launch(void* const* d_in, const int* in_sizes, int n_in,
                              void* d_out, int out_size, void* d_ws, size_t ws_size,
                              hipStream_t stream) {
    const float* features = (const float*)d_in[0];
    const int* src = (const int*)d_in[1];
    const int* dst = (const int*)d_in[2];
    const float* W1 = (const float*)d_in[3];
    const float* b1 = (const float*)d_in[4];
    const float* W2 = (const float*)d_in[5];
    const float* b2 = (const float*)d_in[6];
    const float* Wh = (const float*)d_in[7];
    const float* bh = (const float*)d_in[8];
    const float* gamma = (const float*)d_in[9];
    const float* beta = (const float*)d_in[10];
    const float* Wo = (const float*)d_in[11];
    const float* bo = (const float*)d_in[12];
    float* out = (float*)d_out;

    char* w = (char*)d_ws;
    auto alloc = [&](size_t bytes) -> void* {
        void* p = (void*)w;
        w += (bytes + 255) & ~(size_t)255;
        return p;
    };
    ushort* fb = (ushort*)alloc((size_t)NN * DIM * 2);   // features bf16; later h2 bf16
    ushort* ab = (ushort*)alloc((size_t)NN * DIM * 2);   // agg output bf16; later hm bf16
    ushort* hb = (ushort*)alloc((size_t)NN * DIM * 2);   // h1 bf16
    ushort* W1t = (ushort*)alloc((size_t)DIM * DIM * 2);
    ushort* W2t = (ushort*)alloc((size_t)DIM * DIM * 2);
    ushort* Wht = (ushort*)alloc((size_t)MLPH * DIM * 2);
    int* adj = (int*)alloc((size_t)NE * 4);
    int* counts = (int*)alloc((size_t)NN * 4);
    int* rowstart = (int*)alloc((size_t)(NN + 1) * 4);
    int* cursor = (int*)alloc((size_t)NN * 4);
    int* partial = (int*)alloc(256 * 4);
    float* gsum = (float*)alloc(MLPH * 4);
    float* gsq = (float*)alloc(MLPH * 4);
    float* Wo2 = (float*)alloc(MLPH * 2 * 4);
    float* bo2 = (float*)alloc(2 * 4);

    hipMemsetAsync(counts, 0, (size_t)NN * 4, stream);
    hipMemsetAsync(gsum, 0, MLPH * 4, stream);
    hipMemsetAsync(gsq, 0, MLPH * 4, stream);

    const int NB = (NN + 255) / 256;  // 196

    // CSR build (parallel scan)
    k_hist<<<(NE + 255) / 256, 256, 0, stream>>>(dst, counts);
    k_part<<<NB, 256, 0, stream>>>(counts, partial);
    k_scanp<<<1, 256, 0, stream>>>(partial, rowstart, NB);
    k_scan2<<<NB, 256, 0, stream>>>(counts, partial, rowstart, cursor);
    k_fill<<<(NE + 255) / 256, 256, 0, stream>>>(src, dst, cursor, adj);

    // conversions
    const int n4 = NN * DIM / 4;
    k_cvt<<<(n4 + 255) / 256, 256, 0, stream>>>(features, fb, n4);
    const int WT = 2 * 512 * 512 + MLPH * 512;
    k_wt3<<<(WT + 255) / 256, 256, 0, stream>>>(W1, W2, Wh, W1t, W2t, Wht);

    const int MBr = (NN + 255) / 256;  // 196 row-panels of 256
    const int G512 = 4 * MBr;          // 784 blocks (784 % 8 == 0)
    const int G200 = 2 * MBr;          // 392 blocks (392 % 8 == 0)

    // layer 1
    k_agg_bf<<<(NN + 3) / 4, 256, 0, stream>>>(fb, rowstart, adj, ab);
    k_ggemm<DIM, 1><<<G512, 512, 0, stream>>>(ab, W1t, b1, nullptr, hb, NN);
    // layer 2 (h2 -> fb)
    k_agg_bf<<<(NN + 3) / 4, 256, 0, stream>>>(hb, rowstart, adj, ab);
    k_ggemm<DIM, 1><<<G512, 512, 0, stream>>>(ab, W2t, b2, nullptr, fb, NN);
    // MLP hidden: hm = relu(h2 @ Wh + bh), bf16 out into ab (free after gemm2)
    k_ggemm<MLPH, 1><<<G200, 512, 0, stream>>>(fb, Wht, bh, nullptr, ab, NN);
    // BatchNorm stats + fold into Wo/bo
    k_bnstat<<<512, 256, 0, stream>>>(ab, gsum, gsq);
    k_bnfin<<<1, 256, 0, stream>>>(gsum, gsq, gamma, beta, Wo, bo, Wo2, bo2);
    // output
    k_out<<<(NN * 64 + 511) / 512, 512, 0, stream>>>(ab, Wo2, bo2, out);
}